// Round 2
// baseline (318.869 us; speedup 1.0000x reference)
//
#include <hip/hip_runtime.h>
#include <hip/hip_bf16.h>
#include <math.h>

// Problem constants (from setup_inputs): B=8192, E=16, H=1024
#define B_SZ 8192
#define H_SZ 1024
#define E_SZ 16
#define NT   64      // 8192 / 128 tiles per dimension
#define BM   128     // tile rows/cols
#define BK   32      // K-step (bf16 elems) = 64 bytes
#define NK   (H_SZ / BK)
#define SIM_THR 0.8f

typedef __bf16 bf16_t;
typedef __bf16 bf16x8 __attribute__((ext_vector_type(8)));
typedef __bf16 bf16x4 __attribute__((ext_vector_type(4)));
typedef float  floatx4 __attribute__((ext_vector_type(4)));

// ---------------- workspace layout (byte offsets into d_ws) ----------------
#define OFF_NE   4096
#define OFF_L    65536
#define OFF_P    (65536 + 524288)
#define OFF_EMB  2097152

// direct-to-LDS 16B DMA: lane l of the wave lands at ldsbase + l*16
__device__ __forceinline__ void gload16(const void* g, void* l) {
    __builtin_amdgcn_global_load_lds(
        (const __attribute__((address_space(1))) void*)g,
        (__attribute__((address_space(3))) void*)l, 16, 0, 0);
}

// ---------------------------------------------------------------------------
// Kernel 1: per-row log_softmax / softmax / negative entropy. One thread/row.
// ---------------------------------------------------------------------------
__global__ void softmax_prep(const float* __restrict__ rp,
                             float* __restrict__ L, float* __restrict__ P,
                             float* __restrict__ ne,
                             float* __restrict__ gsum, unsigned int* __restrict__ gcnt) {
    int i = blockIdx.x * blockDim.x + threadIdx.x;
    if (i == 0) { *gsum = 0.f; *gcnt = 0u; }
    if (i >= B_SZ) return;
    const float* x = rp + i * E_SZ;
    float v[E_SZ];
    float m = -INFINITY;
#pragma unroll
    for (int k = 0; k < E_SZ; k++) { v[k] = x[k]; m = fmaxf(m, v[k]); }
    float s = 0.f;
#pragma unroll
    for (int k = 0; k < E_SZ; k++) s += expf(v[k] - m);
    float lse = m + logf(s);
    float nent = 0.f;
#pragma unroll
    for (int k = 0; k < E_SZ; k++) {
        float l = v[k] - lse;
        float p = expf(l);
        L[i * E_SZ + k] = l;
        P[i * E_SZ + k] = p;
        nent += p * l;
    }
    ne[i] = nent;
}

// ---------------------------------------------------------------------------
// Kernel 2: L2-normalize each embedding row and convert to bf16.
// ---------------------------------------------------------------------------
__global__ void normalize_emb(const float* __restrict__ emb, bf16_t* __restrict__ out) {
    int gwave = (blockIdx.x * blockDim.x + threadIdx.x) >> 6;
    int lane  = threadIdx.x & 63;
    if (gwave >= B_SZ) return;
    const float4* row = (const float4*)(emb + (size_t)gwave * H_SZ);
    float4 v[4];
    float ss = 0.f;
#pragma unroll
    for (int p = 0; p < 4; p++) {
        v[p] = row[p * 64 + lane];
        ss += v[p].x * v[p].x + v[p].y * v[p].y + v[p].z * v[p].z + v[p].w * v[p].w;
    }
#pragma unroll
    for (int off = 32; off > 0; off >>= 1) ss += __shfl_down(ss, off, 64);
    ss = __shfl(ss, 0, 64);
    float inv = rsqrtf(ss);
    bf16x4* orow = (bf16x4*)(out + (size_t)gwave * H_SZ);
#pragma unroll
    for (int p = 0; p < 4; p++) {
        bf16x4 o;
        o.x = (__bf16)(v[p].x * inv);
        o.y = (__bf16)(v[p].y * inv);
        o.z = (__bf16)(v[p].z * inv);
        o.w = (__bf16)(v[p].w * inv);
        orow[p * 64 + lane] = o;
    }
}

// g(r) = number of upper-triangle tiles in rows < r
__device__ __forceinline__ int tri_g(int r) { return r * (2 * NT + 1 - r) / 2; }

// ---------------------------------------------------------------------------
// Kernel 3: upper-triangle 128x128 sim tiles via bf16 MFMA with
// global_load_lds double-buffered staging (single barrier per K-step),
// fused mask + KL accumulate.
// ---------------------------------------------------------------------------
__global__ __launch_bounds__(256)
void sim_kl_kernel(const bf16_t* __restrict__ emb,
                   const float* __restrict__ Lm, const float* __restrict__ Pm,
                   const float* __restrict__ ne,
                   float* __restrict__ gsum, unsigned int* __restrict__ gcnt) {
    // unpadded tiles: [128 rows][32 bf16] = 8 KB each; 2 buffers each for A,B
    __shared__ __align__(16) bf16_t As[2][BM * BK];
    __shared__ __align__(16) bf16_t Bs[2][BM * BK];
    __shared__ float redf[4];
    __shared__ unsigned int redc[4];

    // --- linear block id -> (bi, bj) with bj >= bi ---
    int t = blockIdx.x;
    float disc = (float)((2 * NT + 1) * (2 * NT + 1) - 8 * t);
    int bi = (int)(((float)(2 * NT + 1) - sqrtf(disc)) * 0.5f);
    if (bi < 0) bi = 0;
    if (bi > NT - 1) bi = NT - 1;
    while (bi + 1 <= NT - 1 && tri_g(bi + 1) <= t) bi++;
    while (bi > 0 && tri_g(bi) > t) bi--;
    int bj = bi + (t - tri_g(bi));
    const bool diag = (bi == bj);
    const int rowI = bi * BM, rowJ = bj * BM;

    const int tid  = threadIdx.x;
    const int lane = tid & 63;
    const int wave = tid >> 6;
    const int wr = (wave >> 1) * 64;   // wave quadrant row
    const int wc = (wave & 1) * 64;    // wave quadrant col
    const int quad = lane >> 4;
    const int l16  = lane & 15;

    floatx4 acc[4][4];
#pragma unroll
    for (int mi = 0; mi < 4; mi++)
#pragma unroll
        for (int ni = 0; ni < 4; ni++) {
            floatx4 z = {0.f, 0.f, 0.f, 0.f};
            acc[mi][ni] = z;
        }

    // --- DMA staging geometry ---
    // wave w covers rows [32w, 32w+32) of each tile via 2 instructions/operand.
    // lane l -> row 32w + 16q + (l>>2), byte-col (l&3)*16 of the 64-B K-slice.
    const char* gA = (const char*)emb + (size_t)(rowI + 32 * wave + (lane >> 2)) * (H_SZ * 2) + (lane & 3) * 16;
    const char* gB = (const char*)emb + (size_t)(rowJ + 32 * wave + (lane >> 2)) * (H_SZ * 2) + (lane & 3) * 16;
    const int ldsOff = 32 * wave * 64;   // bytes, wave-uniform

    // prologue: stage tile 0 into buffer 0
    {
        char* la = (char*)&As[0][0] + ldsOff;
        char* lb = (char*)&Bs[0][0] + ldsOff;
        gload16(gA, la);
        gload16(gA + 16 * (H_SZ * 2), la + 1024);
        gload16(gB, lb);
        gload16(gB + 16 * (H_SZ * 2), lb + 1024);
    }

    for (int kt = 0; kt < NK; kt++) {
        const int b = kt & 1;
        __syncthreads();   // s_waitcnt vmcnt(0) lgkmcnt(0) + s_barrier: tile kt visible
        if (kt + 1 < NK) { // issue tile kt+1 DMA into the other buffer; overlaps MFMA below
            const char* ga = gA + (size_t)(kt + 1) * (BK * 2);
            const char* gb = gB + (size_t)(kt + 1) * (BK * 2);
            char* la = (char*)&As[b ^ 1][0] + ldsOff;
            char* lb = (char*)&Bs[b ^ 1][0] + ldsOff;
            gload16(ga, la);
            gload16(ga + 16 * (H_SZ * 2), la + 1024);
            gload16(gb, lb);
            gload16(gb + 16 * (H_SZ * 2), lb + 1024);
        }

        const bf16_t* Ab = &As[b][0];
        const bf16_t* Bb = &Bs[b][0];
        bf16x8 af[4], bfr[4];
#pragma unroll
        for (int mi = 0; mi < 4; mi++)
            af[mi] = *(const bf16x8*)(Ab + (wr + mi * 16 + l16) * BK + quad * 8);
#pragma unroll
        for (int ni = 0; ni < 4; ni++)
            bfr[ni] = *(const bf16x8*)(Bb + (wc + ni * 16 + l16) * BK + quad * 8);
#pragma unroll
        for (int mi = 0; mi < 4; mi++)
#pragma unroll
            for (int ni = 0; ni < 4; ni++)
                acc[mi][ni] = __builtin_amdgcn_mfma_f32_16x16x32_bf16(
                    af[mi], bfr[ni], acc[mi][ni], 0, 0, 0);
    }

    // --- epilogue: masked KL accumulate ---
    // C/D layout (16x16x32): col = lane&15, row = (lane>>4)*4 + reg
    float fsum = 0.f;
    unsigned int lcnt = 0;
#pragma unroll
    for (int mi = 0; mi < 4; mi++) {
#pragma unroll
        for (int ni = 0; ni < 4; ni++) {
#pragma unroll
            for (int r = 0; r < 4; r++) {
                int i = rowI + wr + mi * 16 + quad * 4 + r;
                int j = rowJ + wc + ni * 16 + l16;
                float sim = acc[mi][ni][r];
                if (sim > SIM_THR && i != j) {
                    const float* Li = Lm + i * E_SZ;
                    const float* Pj = Pm + j * E_SZ;
                    float d = 0.f;
#pragma unroll
                    for (int k = 0; k < E_SZ; k++) d += Li[k] * Pj[k];
                    float s = ne[j] - d;
                    if (!diag) {
                        const float* Lj = Lm + j * E_SZ;
                        const float* Pi = Pm + i * E_SZ;
                        float d2 = 0.f;
#pragma unroll
                        for (int k = 0; k < E_SZ; k++) d2 += Lj[k] * Pi[k];
                        s += ne[i] - d2;
                        lcnt += 2;
                    } else {
                        lcnt += 1;
                    }
                    fsum += s;
                }
            }
        }
    }

#pragma unroll
    for (int off = 32; off > 0; off >>= 1) {
        fsum += __shfl_down(fsum, off, 64);
        lcnt += __shfl_down(lcnt, off, 64);
    }
    if (lane == 0) { redf[wave] = fsum; redc[wave] = lcnt; }
    __syncthreads();
    if (tid == 0) {
        float s = redf[0] + redf[1] + redf[2] + redf[3];
        unsigned int c = redc[0] + redc[1] + redc[2] + redc[3];
        if (c > 0u) {
            atomicAdd(gsum, s);
            atomicAdd(gcnt, c);
        }
    }
}

// ---------------------------------------------------------------------------
__global__ void finalize_out(const float* __restrict__ gsum,
                             const unsigned int* __restrict__ gcnt,
                             float* __restrict__ out) {
    unsigned int c = *gcnt;
    out[0] = (c > 0u) ? (*gsum / (float)c) : 0.f;   // WEIGHT = 1.0
}

// ---------------------------------------------------------------------------
extern "C" void kernel_launch(void* const* d_in, const int* in_sizes, int n_in,
                              void* d_out, int out_size, void* d_ws, size_t ws_size,
                              hipStream_t stream) {
    const float* rp  = (const float*)d_in[0];   // routing_probs [8192,16] f32
    const float* emb = (const float*)d_in[1];   // input_embeddings [8192,1024] f32
    float* out = (float*)d_out;

    char* ws = (char*)d_ws;
    float*        gsum = (float*)(ws + 0);
    unsigned int* gcnt = (unsigned int*)(ws + 4);
    float*        ne   = (float*)(ws + OFF_NE);
    float*        Lm   = (float*)(ws + OFF_L);
    float*        Pm   = (float*)(ws + OFF_P);
    bf16_t*       embb = (bf16_t*)(ws + OFF_EMB);

    softmax_prep<<<B_SZ / 256, 256, 0, stream>>>(rp, Lm, Pm, ne, gsum, gcnt);
    normalize_emb<<<B_SZ / 4, 256, 0, stream>>>(emb, embb);
    const int ntri = NT * (NT + 1) / 2;  // 2080 upper-triangle tiles
    sim_kl_kernel<<<ntri, 256, 0, stream>>>(embb, Lm, Pm, ne, gsum, gcnt);
    finalize_out<<<1, 1, 0, stream>>>(gsum, gcnt, out);
}

// Round 3
// 270.756 us; speedup vs baseline: 1.1777x; 1.1777x over previous
//
#include <hip/hip_runtime.h>
#include <hip/hip_bf16.h>
#include <math.h>

// Problem constants: B=8192, E=16, H=1024
#define B_SZ 8192
#define H_SZ 1024        // elements per row; ALSO bytes per row in fp8
#define E_SZ 16
#define NT   64          // 8192/128 panels
#define BM   128
#define BKB  64          // K-tile in BYTES (fp8) = 64 elems = 2 MFMA K-steps
#define NK   (H_SZ / BKB)
#define SIM_THR 0.8f

typedef float floatx4 __attribute__((ext_vector_type(4)));

// ---------------- workspace layout ----------------
#define OFF_NE   4096
#define OFF_L    65536
#define OFF_P    (65536 + 524288)
#define OFF_EMB  2097152   // fp8 emb: 8 MB

__device__ __forceinline__ void gload16(const void* g, void* l) {
    __builtin_amdgcn_global_load_lds(
        (const __attribute__((address_space(1))) void*)g,
        (__attribute__((address_space(3))) void*)l, 16, 0, 0);
}

// ---------------------------------------------------------------------------
__global__ void softmax_prep(const float* __restrict__ rp,
                             float* __restrict__ L, float* __restrict__ P,
                             float* __restrict__ ne,
                             float* __restrict__ gsum, unsigned int* __restrict__ gcnt) {
    int i = blockIdx.x * blockDim.x + threadIdx.x;
    if (i == 0) { *gsum = 0.f; *gcnt = 0u; }
    if (i >= B_SZ) return;
    const float* x = rp + i * E_SZ;
    float v[E_SZ];
    float m = -INFINITY;
#pragma unroll
    for (int k = 0; k < E_SZ; k++) { v[k] = x[k]; m = fmaxf(m, v[k]); }
    float s = 0.f;
#pragma unroll
    for (int k = 0; k < E_SZ; k++) s += expf(v[k] - m);
    float lse = m + logf(s);
    float nent = 0.f;
#pragma unroll
    for (int k = 0; k < E_SZ; k++) {
        float l = v[k] - lse;
        float p = expf(l);
        L[i * E_SZ + k] = l;
        P[i * E_SZ + k] = p;
        nent += p * l;
    }
    ne[i] = nent;
}

// ---------------------------------------------------------------------------
// L2-normalize each row and emit OCP fp8-e4m3 (HW packed cvt).
// ---------------------------------------------------------------------------
__global__ void normalize_emb_fp8(const float* __restrict__ emb,
                                  unsigned char* __restrict__ out) {
    int gwave = (blockIdx.x * blockDim.x + threadIdx.x) >> 6;
    int lane  = threadIdx.x & 63;
    if (gwave >= B_SZ) return;
    const float4* row = (const float4*)(emb + (size_t)gwave * H_SZ);
    float4 v[4];
    float ss = 0.f;
#pragma unroll
    for (int p = 0; p < 4; p++) {
        v[p] = row[p * 64 + lane];
        ss += v[p].x * v[p].x + v[p].y * v[p].y + v[p].z * v[p].z + v[p].w * v[p].w;
    }
#pragma unroll
    for (int off = 32; off > 0; off >>= 1) ss += __shfl_down(ss, off, 64);
    ss = __shfl(ss, 0, 64);
    float inv = rsqrtf(ss);
    unsigned int* orow = (unsigned int*)(out + (size_t)gwave * H_SZ);
#pragma unroll
    for (int p = 0; p < 4; p++) {
        int pk = __builtin_amdgcn_cvt_pk_fp8_f32(v[p].x * inv, v[p].y * inv, 0, false);
        pk = __builtin_amdgcn_cvt_pk_fp8_f32(v[p].z * inv, v[p].w * inv, pk, true);
        orow[p * 64 + lane] = (unsigned int)pk;
    }
}

// count of n in [lo,hi] with n&7==r; *first = smallest such n
__device__ __forceinline__ int cnt_range(int lo, int hi, int r, int* first) {
    int lo2 = lo + ((r - lo) & 7);
    *first = lo2;
    return (lo2 > hi) ? 0 : ((hi - lo2) >> 3) + 1;
}

// ---------------------------------------------------------------------------
// Main: fp8 MFMA sim tiles, owner-computes XCD partition, fused KL epilogue.
// XCD x = blockIdx%8 owns bj panels with g(bj)=x, g(bj)= bj<32? bj&7 : 7-(bj&7)
// (exactly 260 tiles per XCD). Within an XCD tiles are bi-ordered so the
// streamed A panel is reused across its ~8 resident-B tiles.
// ---------------------------------------------------------------------------
__global__ __launch_bounds__(256)
void sim_kl_kernel(const unsigned char* __restrict__ emb8,
                   const float* __restrict__ Lm, const float* __restrict__ Pm,
                   const float* __restrict__ ne,
                   float* __restrict__ gsum, unsigned int* __restrict__ gcnt) {
    __shared__ __align__(16) char As[2][BM * BKB];   // 8 KB per buffer
    __shared__ __align__(16) char Bs[2][BM * BKB];
    __shared__ float redf[4];
    __shared__ unsigned int redc[4];

    // --- blockIdx -> (bi, bj) via owner-computes enumeration ---
    const int x = blockIdx.x & 7;
    int s = blockIdx.x >> 3;            // 0..259
    int bi = 0, bj = 0;
    for (bi = 0; bi < NT; bi++) {
        int f1, f2;
        int n1 = (bi <= 31) ? cnt_range(bi, 31, x, &f1) : 0;
        int n2 = cnt_range(bi < 32 ? 32 : bi, 63, 7 - x, &f2);
        if (s < n1) { bj = f1 + 8 * s; break; }
        s -= n1;
        if (s < n2) { bj = f2 + 8 * s; break; }
        s -= n2;
    }
    const bool diag = (bi == bj);
    const int rowI = bi * BM, rowJ = bj * BM;

    const int tid  = threadIdx.x;
    const int lane = tid & 63;
    const int wave = tid >> 6;
    const int wr = (wave >> 1) * 64;
    const int wc = (wave & 1) * 64;
    const int quad = lane >> 4;
    const int l16  = lane & 15;

    floatx4 acc[4][4];
#pragma unroll
    for (int mi = 0; mi < 4; mi++)
#pragma unroll
        for (int ni = 0; ni < 4; ni++) {
            floatx4 z = {0.f, 0.f, 0.f, 0.f};
            acc[mi][ni] = z;
        }

    // --- DMA geometry: rows are 64 B; one gload16 covers 16 rows/wave.
    // XOR-swizzle which 16B chunk each lane fetches so fragment ds_reads are
    // conflict-light; LDS tile stays row-major [128][64] in lane order.
    const int swz = ((lane & 3) ^ ((lane >> 3) & 3)) * 16;
    const char* gA = (const char*)emb8 + (size_t)(rowI + 32 * wave + (lane >> 2)) * H_SZ + swz;
    const char* gB = (const char*)emb8 + (size_t)(rowJ + 32 * wave + (lane >> 2)) * H_SZ + swz;
    const int ldsW = 32 * wave * BKB;   // wave-uniform LDS base offset

    {   // prologue: stage K-tile 0 into buffer 0
        char* la = &As[0][0] + ldsW;
        char* lb = &Bs[0][0] + ldsW;
        gload16(gA, la); gload16(gA + 16 * H_SZ, la + 1024);
        gload16(gB, lb); gload16(gB + 16 * H_SZ, lb + 1024);
    }

    const int keyl = (l16 >> 1) & 3;
    for (int kt = 0; kt < NK; kt++) {
        const int b = kt & 1;
        __syncthreads();                 // tile kt visible
        if (kt + 1 < NK) {               // prefetch kt+1, overlaps MFMAs below
            const char* ga = gA + (kt + 1) * BKB;
            const char* gb = gB + (kt + 1) * BKB;
            char* la = &As[b ^ 1][0] + ldsW;
            char* lb = &Bs[b ^ 1][0] + ldsW;
            gload16(ga, la); gload16(ga + 16 * H_SZ, la + 1024);
            gload16(gb, lb); gload16(gb + 16 * H_SZ, lb + 1024);
        }

        const char* Ab = &As[b][0];
        const char* Bb = &Bs[b][0];
        long af[2][4], bfm[2][4];
#pragma unroll
        for (int mi = 0; mi < 4; mi++) {
            int R = wr + mi * 16 + l16;
#pragma unroll
            for (int ks = 0; ks < 2; ks++) {
                int c4 = ks * 2 + (quad >> 1);
                af[ks][mi] = *(const long*)(Ab + R * BKB + ((c4 ^ keyl) << 4) + (quad & 1) * 8);
            }
        }
#pragma unroll
        for (int ni = 0; ni < 4; ni++) {
            int R = wc + ni * 16 + l16;
#pragma unroll
            for (int ks = 0; ks < 2; ks++) {
                int c4 = ks * 2 + (quad >> 1);
                bfm[ks][ni] = *(const long*)(Bb + R * BKB + ((c4 ^ keyl) << 4) + (quad & 1) * 8);
            }
        }
#pragma unroll
        for (int ks = 0; ks < 2; ks++)
#pragma unroll
            for (int mi = 0; mi < 4; mi++)
#pragma unroll
                for (int ni = 0; ni < 4; ni++)
                    acc[mi][ni] = __builtin_amdgcn_mfma_f32_16x16x32_fp8_fp8(
                        af[ks][mi], bfm[ks][ni], acc[mi][ni], 0, 0, 0);
    }

    // --- epilogue: masked KL accumulate (C/D: col=lane&15, row=quad*4+reg) ---
    float fsum = 0.f;
    unsigned int lcnt = 0;
#pragma unroll
    for (int mi = 0; mi < 4; mi++) {
#pragma unroll
        for (int ni = 0; ni < 4; ni++) {
#pragma unroll
            for (int r = 0; r < 4; r++) {
                int i = rowI + wr + mi * 16 + quad * 4 + r;
                int j = rowJ + wc + ni * 16 + l16;
                float sim = acc[mi][ni][r];
                if (sim > SIM_THR && i != j) {
                    const float* Li = Lm + i * E_SZ;
                    const float* Pj = Pm + j * E_SZ;
                    float d = 0.f;
#pragma unroll
                    for (int k = 0; k < E_SZ; k++) d += Li[k] * Pj[k];
                    float sv = ne[j] - d;
                    if (!diag) {
                        const float* Lj = Lm + j * E_SZ;
                        const float* Pi = Pm + i * E_SZ;
                        float d2 = 0.f;
#pragma unroll
                        for (int k = 0; k < E_SZ; k++) d2 += Lj[k] * Pi[k];
                        sv += ne[i] - d2;
                        lcnt += 2;
                    } else {
                        lcnt += 1;
                    }
                    fsum += sv;
                }
            }
        }
    }

#pragma unroll
    for (int off = 32; off > 0; off >>= 1) {
        fsum += __shfl_down(fsum, off, 64);
        lcnt += __shfl_down(lcnt, off, 64);
    }
    if (lane == 0) { redf[wave] = fsum; redc[wave] = lcnt; }
    __syncthreads();
    if (tid == 0) {
        float sv = redf[0] + redf[1] + redf[2] + redf[3];
        unsigned int c = redc[0] + redc[1] + redc[2] + redc[3];
        if (c > 0u) {
            atomicAdd(gsum, sv);
            atomicAdd(gcnt, c);
        }
    }
}

// ---------------------------------------------------------------------------
__global__ void finalize_out(const float* __restrict__ gsum,
                             const unsigned int* __restrict__ gcnt,
                             float* __restrict__ out) {
    unsigned int c = *gcnt;
    out[0] = (c > 0u) ? (*gsum / (float)c) : 0.f;   // WEIGHT = 1.0
}

// ---------------------------------------------------------------------------
extern "C" void kernel_launch(void* const* d_in, const int* in_sizes, int n_in,
                              void* d_out, int out_size, void* d_ws, size_t ws_size,
                              hipStream_t stream) {
    const float* rp  = (const float*)d_in[0];
    const float* emb = (const float*)d_in[1];
    float* out = (float*)d_out;

    char* ws = (char*)d_ws;
    float*         gsum = (float*)(ws + 0);
    unsigned int*  gcnt = (unsigned int*)(ws + 4);
    float*         ne   = (float*)(ws + OFF_NE);
    float*         Lm   = (float*)(ws + OFF_L);
    float*         Pm   = (float*)(ws + OFF_P);
    unsigned char* emb8 = (unsigned char*)(ws + OFF_EMB);

    softmax_prep<<<B_SZ / 256, 256, 0, stream>>>(rp, Lm, Pm, ne, gsum, gcnt);
    normalize_emb_fp8<<<B_SZ / 4, 256, 0, stream>>>(emb, emb8);
    const int ntri = NT * (NT + 1) / 2;  // 2080
    sim_kl_kernel<<<ntri, 256, 0, stream>>>(emb8, Lm, Pm, ne, gsum, gcnt);
    finalize_out<<<1, 1, 0, stream>>>(gsum, gcnt, out);
}

// Round 4
// 182.076 us; speedup vs baseline: 1.7513x; 1.4870x over previous
//
#include <hip/hip_runtime.h>
#include <hip/hip_bf16.h>
#include <math.h>

// Problem constants: B=8192, E=16, H=1024
#define B_SZ 8192
#define H_SZ 1024        // elements per row; ALSO bytes per row in fp8
#define E_SZ 16
#define NT   64          // 8192/128 panels
#define BM   128
#define BKB  64          // K-tile in BYTES (fp8) = 64 elems = 2 MFMA K-steps
#define NK   (H_SZ / BKB)
#define SIM_THR 0.8f

typedef float floatx4 __attribute__((ext_vector_type(4)));

// ---------------- workspace layout ----------------
#define OFF_NE   4096
#define OFF_L    65536
#define OFF_P    (65536 + 524288)
#define OFF_EMB  2097152   // fp8 emb: 8 MB

__device__ __forceinline__ void gload16(const void* g, void* l) {
    __builtin_amdgcn_global_load_lds(
        (const __attribute__((address_space(1))) void*)g,
        (__attribute__((address_space(3))) void*)l, 16, 0, 0);
}

// ---------------------------------------------------------------------------
// Fused prep: blocks 0..2047 normalize embeddings -> fp8; blocks 2048..2079
// compute per-row log_softmax/softmax/neg-entropy.
// ---------------------------------------------------------------------------
__global__ void prep_kernel(const float* __restrict__ rp,
                            const float* __restrict__ emb,
                            unsigned char* __restrict__ out8,
                            float* __restrict__ L, float* __restrict__ P,
                            float* __restrict__ ne,
                            float* __restrict__ gsum, unsigned int* __restrict__ gcnt) {
    const int b = blockIdx.x;
    if (b < 2048) {
        int gwave = b * 4 + (threadIdx.x >> 6);
        int lane  = threadIdx.x & 63;
        const float4* row = (const float4*)(emb + (size_t)gwave * H_SZ);
        float4 v[4];
        float ss = 0.f;
#pragma unroll
        for (int p = 0; p < 4; p++) {
            v[p] = row[p * 64 + lane];
            ss += v[p].x * v[p].x + v[p].y * v[p].y + v[p].z * v[p].z + v[p].w * v[p].w;
        }
#pragma unroll
        for (int off = 32; off > 0; off >>= 1) ss += __shfl_down(ss, off, 64);
        ss = __shfl(ss, 0, 64);
        float inv = rsqrtf(ss);
        unsigned int* orow = (unsigned int*)(out8 + (size_t)gwave * H_SZ);
#pragma unroll
        for (int p = 0; p < 4; p++) {
            int pk = __builtin_amdgcn_cvt_pk_fp8_f32(v[p].x * inv, v[p].y * inv, 0, false);
            pk = __builtin_amdgcn_cvt_pk_fp8_f32(v[p].z * inv, v[p].w * inv, pk, true);
            orow[p * 64 + lane] = (unsigned int)pk;
        }
    } else {
        int i = (b - 2048) * 256 + threadIdx.x;
        if (i == 0) { *gsum = 0.f; *gcnt = 0u; }
        if (i >= B_SZ) return;
        const float* x = rp + i * E_SZ;
        float v[E_SZ];
        float m = -INFINITY;
#pragma unroll
        for (int k = 0; k < E_SZ; k++) { v[k] = x[k]; m = fmaxf(m, v[k]); }
        float s = 0.f;
#pragma unroll
        for (int k = 0; k < E_SZ; k++) s += expf(v[k] - m);
        float lse = m + logf(s);
        float nent = 0.f;
#pragma unroll
        for (int k = 0; k < E_SZ; k++) {
            float l = v[k] - lse;
            float p = expf(l);
            L[i * E_SZ + k] = l;
            P[i * E_SZ + k] = p;
            nent += p * l;
        }
        ne[i] = nent;
    }
}

// count of n in [lo,hi] with n&7==r; *first = smallest such n
__device__ __forceinline__ int cnt_range(int lo, int hi, int r, int* first) {
    int lo2 = lo + ((r - lo) & 7);
    *first = lo2;
    return (lo2 > hi) ? 0 : ((hi - lo2) >> 3) + 1;
}

// ---------------------------------------------------------------------------
// Main: fp8 MFMA sim tiles (owner-computes XCD partition), then
// compact-and-process epilogue: ballot-compact masked (i,j) pairs into an
// LDS list (union over the dead staging buffers), process with dense lanes
// and float4 loads. Worst case 16384 entries = 32 KB = exactly the union.
// ---------------------------------------------------------------------------
__global__ __launch_bounds__(256)
void sim_kl_kernel(const unsigned char* __restrict__ emb8,
                   const float* __restrict__ Lm, const float* __restrict__ Pm,
                   const float* __restrict__ ne,
                   float* __restrict__ gsum, unsigned int* __restrict__ gcnt) {
    __shared__ __align__(16) char smem[4][BM * BKB];  // As0,As1,Bs0,Bs1 | list
    __shared__ float redf[4];
    __shared__ unsigned int redc[4];
    __shared__ int cnt_s;

    // --- blockIdx -> (bi, bj): XCD x owns bj panels with g(bj)==x ---
    const int x = blockIdx.x & 7;
    int s = blockIdx.x >> 3;            // 0..259
    int bi = 0, bj = 0;
    for (bi = 0; bi < NT; bi++) {
        int f1, f2;
        int n1 = (bi <= 31) ? cnt_range(bi, 31, x, &f1) : 0;
        int n2 = cnt_range(bi < 32 ? 32 : bi, 63, 7 - x, &f2);
        if (s < n1) { bj = f1 + 8 * s; break; }
        s -= n1;
        if (s < n2) { bj = f2 + 8 * s; break; }
        s -= n2;
    }
    const bool diag = (bi == bj);
    const int rowI = bi * BM, rowJ = bj * BM;

    const int tid  = threadIdx.x;
    const int lane = tid & 63;
    const int wave = tid >> 6;
    const int wr = (wave >> 1) * 64;
    const int wc = (wave & 1) * 64;
    const int quad = lane >> 4;
    const int l16  = lane & 15;

    floatx4 acc[4][4];
#pragma unroll
    for (int mi = 0; mi < 4; mi++)
#pragma unroll
        for (int ni = 0; ni < 4; ni++) {
            floatx4 z = {0.f, 0.f, 0.f, 0.f};
            acc[mi][ni] = z;
        }

    // --- DMA geometry: rows are 64 B; one gload16 covers 16 rows/wave.
    const int swz = ((lane & 3) ^ ((lane >> 3) & 3)) * 16;
    const char* gA = (const char*)emb8 + (size_t)(rowI + 32 * wave + (lane >> 2)) * H_SZ + swz;
    const char* gB = (const char*)emb8 + (size_t)(rowJ + 32 * wave + (lane >> 2)) * H_SZ + swz;
    const int ldsW = 32 * wave * BKB;   // wave-uniform LDS base offset

    {   // prologue: stage K-tile 0 into buffer 0
        char* la = smem[0] + ldsW;
        char* lb = smem[2] + ldsW;
        gload16(gA, la); gload16(gA + 16 * H_SZ, la + 1024);
        gload16(gB, lb); gload16(gB + 16 * H_SZ, lb + 1024);
    }

    const int keyl = (l16 >> 1) & 3;
    for (int kt = 0; kt < NK; kt++) {
        const int b = kt & 1;
        __syncthreads();                 // tile kt visible
        if (kt + 1 < NK) {               // prefetch kt+1, overlaps MFMAs below
            const char* ga = gA + (kt + 1) * BKB;
            const char* gb = gB + (kt + 1) * BKB;
            char* la = smem[b ^ 1] + ldsW;
            char* lb = smem[2 + (b ^ 1)] + ldsW;
            gload16(ga, la); gload16(ga + 16 * H_SZ, la + 1024);
            gload16(gb, lb); gload16(gb + 16 * H_SZ, lb + 1024);
        }

        const char* Ab = smem[b];
        const char* Bb = smem[2 + b];
        long af[2][4], bfm[2][4];
#pragma unroll
        for (int mi = 0; mi < 4; mi++) {
            int R = wr + mi * 16 + l16;
#pragma unroll
            for (int ks = 0; ks < 2; ks++) {
                int c4 = ks * 2 + (quad >> 1);
                af[ks][mi] = *(const long*)(Ab + R * BKB + ((c4 ^ keyl) << 4) + (quad & 1) * 8);
            }
        }
#pragma unroll
        for (int ni = 0; ni < 4; ni++) {
            int R = wc + ni * 16 + l16;
#pragma unroll
            for (int ks = 0; ks < 2; ks++) {
                int c4 = ks * 2 + (quad >> 1);
                bfm[ks][ni] = *(const long*)(Bb + R * BKB + ((c4 ^ keyl) << 4) + (quad & 1) * 8);
            }
        }
#pragma unroll
        for (int ks = 0; ks < 2; ks++)
#pragma unroll
            for (int mi = 0; mi < 4; mi++)
#pragma unroll
                for (int ni = 0; ni < 4; ni++)
                    acc[mi][ni] = __builtin_amdgcn_mfma_f32_16x16x32_fp8_fp8(
                        af[ks][mi], bfm[ks][ni], acc[mi][ni], 0, 0, 0);
    }

    // =================== compact-and-process epilogue ===================
    __syncthreads();                 // all LDS tile reads done: list may reuse
    if (tid == 0) cnt_s = 0;
    __syncthreads();
    unsigned short* list = (unsigned short*)smem;

    // C/D layout: col = lane&15, row = quad*4 + reg
#pragma unroll
    for (int mi = 0; mi < 4; mi++) {
#pragma unroll
        for (int ni = 0; ni < 4; ni++) {
#pragma unroll
            for (int r = 0; r < 4; r++) {
                int il = wr + mi * 16 + quad * 4 + r;
                int jl = wc + ni * 16 + l16;
                bool msk = (acc[mi][ni][r] > SIM_THR) && (rowI + il != rowJ + jl);
                unsigned long long bal = __ballot(msk);
                if (bal) {
                    int leader = __ffsll((long long)bal) - 1;
                    int base = 0;
                    if (lane == leader) base = atomicAdd(&cnt_s, __popcll(bal));
                    base = __shfl(base, leader, 64);
                    if (msk) {
                        int pos = base + __popcll(bal & ((1ull << lane) - 1ull));
                        list[pos] = (unsigned short)((il << 8) | jl);
                    }
                }
            }
        }
    }
    __syncthreads();
    const int n = cnt_s;

    float fsum = 0.f;
    unsigned int lcnt = 0;
    for (int t = tid; t < n; t += 256) {
        int e = list[t];
        int i = rowI + (e >> 8), j = rowJ + (e & 255);
        const float4* Li4 = (const float4*)(Lm + i * E_SZ);
        const float4* Pj4 = (const float4*)(Pm + j * E_SZ);
        float d = 0.f;
#pragma unroll
        for (int q = 0; q < 4; q++) {
            float4 a = Li4[q], bb = Pj4[q];
            d += a.x * bb.x + a.y * bb.y + a.z * bb.z + a.w * bb.w;
        }
        float sv = ne[j] - d;
        unsigned int c = 1;
        if (!diag) {
            const float4* Lj4 = (const float4*)(Lm + j * E_SZ);
            const float4* Pi4 = (const float4*)(Pm + i * E_SZ);
            float d2 = 0.f;
#pragma unroll
            for (int q = 0; q < 4; q++) {
                float4 a = Lj4[q], bb = Pi4[q];
                d2 += a.x * bb.x + a.y * bb.y + a.z * bb.z + a.w * bb.w;
            }
            sv += ne[i] - d2;
            c = 2;
        }
        fsum += sv;
        lcnt += c;
    }

#pragma unroll
    for (int off = 32; off > 0; off >>= 1) {
        fsum += __shfl_down(fsum, off, 64);
        lcnt += __shfl_down(lcnt, off, 64);
    }
    if (lane == 0) { redf[wave] = fsum; redc[wave] = lcnt; }
    __syncthreads();
    if (tid == 0) {
        float sv = redf[0] + redf[1] + redf[2] + redf[3];
        unsigned int c = redc[0] + redc[1] + redc[2] + redc[3];
        if (c > 0u) {
            atomicAdd(gsum, sv);
            atomicAdd(gcnt, c);
        }
    }
}

// ---------------------------------------------------------------------------
__global__ void finalize_out(const float* __restrict__ gsum,
                             const unsigned int* __restrict__ gcnt,
                             float* __restrict__ out) {
    unsigned int c = *gcnt;
    out[0] = (c > 0u) ? (*gsum / (float)c) : 0.f;   // WEIGHT = 1.0
}

// ---------------------------------------------------------------------------
extern "C" void kernel_launch(void* const* d_in, const int* in_sizes, int n_in,
                              void* d_out, int out_size, void* d_ws, size_t ws_size,
                              hipStream_t stream) {
    const float* rp  = (const float*)d_in[0];
    const float* emb = (const float*)d_in[1];
    float* out = (float*)d_out;

    char* ws = (char*)d_ws;
    float*         gsum = (float*)(ws + 0);
    unsigned int*  gcnt = (unsigned int*)(ws + 4);
    float*         ne   = (float*)(ws + OFF_NE);
    float*         Lm   = (float*)(ws + OFF_L);
    float*         Pm   = (float*)(ws + OFF_P);
    unsigned char* emb8 = (unsigned char*)(ws + OFF_EMB);

    prep_kernel<<<2048 + 32, 256, 0, stream>>>(rp, emb, emb8, Lm, Pm, ne, gsum, gcnt);
    const int ntri = NT * (NT + 1) / 2;  // 2080
    sim_kl_kernel<<<ntri, 256, 0, stream>>>(emb8, Lm, Pm, ne, gsum, gcnt);
    finalize_out<<<1, 1, 0, stream>>>(gsum, gcnt, out);
}